// Round 13
// baseline (430.143 us; speedup 1.0000x reference)
//
#include <hip/hip_runtime.h>
#include <hip/hip_bf16.h>
#include <hip/hip_fp16.h>

constexpr int Dc = 128;   // feature dim
constexpr int NG = 32;    // num graphs / batch size

// ---- sentinel: encode a diagnostic code in the output magnitude ----
__global__ void k_sentinel(float* __restrict__ out, float val, int n){
  int i = blockIdx.x*256 + threadIdx.x;
  if (i < n) out[i] = val;
}

// ---- init2: pooled = 0, packed = 0, last block does graph bounds ----
__global__ void k_init2(float* __restrict__ pooled,
                        unsigned long long* __restrict__ packed,
                        const int* __restrict__ batch, int* __restrict__ gs,
                        int N, int nbz){
  if ((int)blockIdx.x == nbz){
    int g = threadIdx.x;
    if (g > NG) return;
    int lo = 0, hi = N;
    while (lo < hi){ int mid = (lo+hi)>>1; if (batch[mid] < g) lo = mid+1; else hi = mid; }
    gs[g] = lo;
    return;
  }
  int i = blockIdx.x*256 + threadIdx.x;
  if (i < NG*Dc) pooled[i] = 0.f;
  if (i < N) packed[i] = 0ULL;
}

// ---- fallback init: q = b_img, qi = b_i (legacy image path only) ----
__global__ void k_init_iq(const float* __restrict__ b_img, float* __restrict__ q,
                          const float* __restrict__ b_i, float* __restrict__ qi,
                          int BI, int IMG){
  int i = blockIdx.x*256 + threadIdx.x;
  if (i < BI) q[i] = b_img[i % IMG];
  if (i < NG*Dc) qi[i] = b_i[i & (Dc-1)];
}

// ---- ONE packed atomic per edge: hi 24 bits = in-degree count,
//      lo 40 bits = 20.20 fixed-point sum of edge weights.
//      Returned old value's count field = this edge's rank within its row. ----
__global__ void k_pack_count(const int* __restrict__ dst, const float* __restrict__ ew,
        unsigned long long* __restrict__ packed, int* __restrict__ rank, int E){
  int e = blockIdx.x*256 + threadIdx.x;
  if (e >= E) return;
  unsigned long long fx = (unsigned long long)(ew[e]*1048576.f + 0.5f);  // 20.20 fixed
  unsigned long long old = atomicAdd(&packed[dst[e]], (1ULL<<40) | fx);
  rank[e] = (int)(old >> 40);
}

// ---- fused unpack + scan_partial: cntN, dis, and per-block count sums ----
__global__ __launch_bounds__(256) void k_dis2s(const unsigned long long* __restrict__ packed,
        float* __restrict__ dis, int* __restrict__ cntN, int* __restrict__ bsum, int N){
  __shared__ int red[256];
  int t = threadIdx.x, i = blockIdx.x*256 + t;
  int c = 0;
  if (i < N){
    unsigned long long p = packed[i];
    c = (int)(p >> 40);
    cntN[i] = c;
    float deg = 1.0f + (float)(p & ((1ULL<<40)-1)) * (1.0f/1048576.0f);
    dis[i] = rsqrtf(deg);
  }
  red[t] = c;
  __syncthreads();
  for (int s = 128; s > 0; s >>= 1){ if (t < s) red[t] += red[t+s]; __syncthreads(); }
  if (t == 0) bsum[blockIdx.x] = red[0];
}

__global__ __launch_bounds__(256) void k_scan_bsum(int* __restrict__ bsum, int nb,
        int* __restrict__ row_start, int N, int E){
  __shared__ int sc[256];
  int t = threadIdx.x;
  int orig = (t < nb) ? bsum[t] : 0;
  sc[t] = orig;
  __syncthreads();
  for (int off = 1; off < 256; off <<= 1){
    int v = (t >= off) ? sc[t-off] : 0;
    __syncthreads();
    sc[t] += v;
    __syncthreads();
  }
  if (t < nb) bsum[t] = sc[t] - orig;   // exclusive
  if (t == 0) row_start[N] = E;
}

__global__ __launch_bounds__(256) void k_scan_final(const int* __restrict__ cnt,
        const int* __restrict__ bsum, int* __restrict__ row_start, int N){
  __shared__ int sc[256];
  int t = threadIdx.x, i = blockIdx.x*256 + t;
  int orig = (i < N) ? cnt[i] : 0;
  sc[t] = orig;
  __syncthreads();
  for (int off = 1; off < 256; off <<= 1){
    int v = (t >= off) ? sc[t-off] : 0;
    __syncthreads();
    sc[t] += v;
    __syncthreads();
  }
  if (i < N) row_start[i] = bsum[blockIdx.x] + sc[t] - orig;
}

// ---- fill CSR, NO atomics: pos = row_start[dst] + rank; one interleaved
//      8B store per edge: (src, dis[s]*ew*dis[d]) ----
__global__ void k_fill2(const int* __restrict__ src, const int* __restrict__ dst,
        const float* __restrict__ ew, const float* __restrict__ dis,
        const int* __restrict__ rank, const int* __restrict__ row_start,
        float2* __restrict__ ewn, int E){
  int e = blockIdx.x*256 + threadIdx.x;
  if (e >= E) return;
  int s = src[e], d = dst[e];
  int pos = row_start[d] + rank[e];
  float2 v;
  v.x = __int_as_float(s);
  v.y = dis[s] * ew[e] * dis[d];
  ewn[pos] = v;
}

// ---- pull aggregation over fp16 xw: 2 nodes/block (1 per wave),
//      lane owns 2 cols (half2 gather = 4B/lane, full 256B row per wave). ----
__global__ __launch_bounds__(128) void k_agg(const __half* __restrict__ xwh,
        const int* __restrict__ row_start, const float2* __restrict__ ewn,
        const float* __restrict__ dis, const float* __restrict__ bias,
        float* __restrict__ xo, int N){
  int n = blockIdx.x*2 + (threadIdx.x >> 6);
  if (n >= N) return;
  int l = threadIdx.x & 63;          // lane: cols 2l, 2l+1
  int c = l << 1;
  float dv = dis[n];
  float2 self = __half22float2(*(const __half2*)&xwh[(size_t)n*Dc + c]);
  float2 acc;
  acc.x = bias[c]   + self.x*dv*dv;
  acc.y = bias[c+1] + self.y*dv*dv;
  int j = row_start[n], j1 = row_start[n+1];
  for (; j + 3 < j1; j += 4){
    float2 e0 = ewn[j],   e1 = ewn[j+1], e2 = ewn[j+2], e3 = ewn[j+3];
    int   s0 = __float_as_int(e0.x), s1 = __float_as_int(e1.x);
    int   s2 = __float_as_int(e2.x), s3 = __float_as_int(e3.x);
    float2 v0 = __half22float2(*(const __half2*)&xwh[(size_t)s0*Dc + c]);
    float2 v1 = __half22float2(*(const __half2*)&xwh[(size_t)s1*Dc + c]);
    float2 v2 = __half22float2(*(const __half2*)&xwh[(size_t)s2*Dc + c]);
    float2 v3 = __half22float2(*(const __half2*)&xwh[(size_t)s3*Dc + c]);
    acc.x += v0.x*e0.y + v1.x*e1.y + v2.x*e2.y + v3.x*e3.y;
    acc.y += v0.y*e0.y + v1.y*e1.y + v2.y*e2.y + v3.y*e3.y;
  }
  for (; j < j1; j++){
    float2 ee = ewn[j];
    float2 v = __half22float2(*(const __half2*)&xwh[(size_t)__float_as_int(ee.x)*Dc + c]);
    acc.x += v.x*ee.y;
    acc.y += v.y*ee.y;
  }
  *(float2*)&xo[(size_t)n*Dc + c] = acc;
}

// ==== image GEMM v6: KS3=32, fp16 partials, 8-row (4-pair) W prefetch ring.
//      Outstanding 4KB/wave x 16 waves/CU ~= 64KB/CU in flight -> stream W_img
//      near achievable HBM BW. All ring indices compile-time (no scratch). ====
constexpr int KS3 = 32;
__global__ __launch_bounds__(256, 4) void k_img_mm3(const float* __restrict__ images,
        const float* __restrict__ Wimg, __half* __restrict__ P, int IMG){
  __shared__ float Ls[NG][KS3];
  int t = threadIdx.x;
  int col = blockIdx.x*512 + (t << 1);
  int k0  = blockIdx.y * KS3;
  for (int i = t; i < NG*KS3; i += 256){
    int b = i >> 5, k = i & (KS3-1);
    Ls[b][k] = images[(size_t)b*IMG + k0 + k];
  }
  __syncthreads();
  float2 acc[NG];
  #pragma unroll
  for (int b = 0; b < NG; b++){ acc[b].x = 0.f; acc[b].y = 0.f; }
  const float* wp = Wimg + (size_t)k0*IMG + col;
  float2 w[8];
  #pragma unroll
  for (int r = 0; r < 8; r++) w[r] = *(const float2*)(wp + (size_t)r*IMG);
  for (int k = 0; k < KS3; k += 8){
    float2 nw[8];
    #pragma unroll
    for (int r = 0; r < 8; r++) nw[r] = w[r];
    if (k + 8 < KS3){
      #pragma unroll
      for (int r = 0; r < 8; r++)
        nw[r] = *(const float2*)(wp + (size_t)(k + 8 + r)*IMG);
    }
    #pragma unroll
    for (int p = 0; p < 4; p++){
      float2 w0 = w[2*p], w1 = w[2*p + 1];
      #pragma unroll
      for (int b = 0; b < NG; b++){
        float2 iv = *(const float2*)&Ls[b][k + 2*p];   // broadcast ds_read_b64
        acc[b].x += iv.x*w0.x + iv.y*w1.x;
        acc[b].y += iv.x*w0.y + iv.y*w1.y;
      }
    }
    #pragma unroll
    for (int r = 0; r < 8; r++) w[r] = nw[r];
  }
  size_t BIs = (size_t)NG*IMG;
  size_t base = (size_t)blockIdx.y*BIs + col;
  #pragma unroll
  for (int b = 0; b < NG; b++)
    *(__half2*)&P[base + (size_t)b*IMG] = __floats2half2_rn(acc[b].x, acc[b].y);
}

// ---- image head v3 (fused): stage Lq[64] = b_img-slice + sum_g Ph, then
//      GEMM slice vs W_i; write per-(b,seg) partials (no atomics). IMG==4096. ----
constexpr int IKS2 = 64;
__global__ __launch_bounds__(128) void k_ihead_mm3(const __half* __restrict__ Ph,
        const float* __restrict__ b_img, const float* __restrict__ Wi,
        float* __restrict__ P2, int IMG, int nseg){
  int b = blockIdx.x, seg = blockIdx.y, t = threadIdx.x;
  const int kseg = 64;                    // IMG / IKS2 with IMG == 4096
  int BI = NG * IMG;
  __shared__ float Ls2[128];
  __shared__ float Lq[64];
  int c = t & 63, gh = t >> 6;
  size_t base = (size_t)b*IMG + seg*kseg + c;
  float part = 0.f;
  for (int g = gh; g < nseg; g += 2)
    part += __half2float(Ph[(size_t)g*BI + base]);
  Ls2[t] = part;
  __syncthreads();
  if (t < 64) Lq[t] = b_img[seg*kseg + t] + Ls2[t] + Ls2[t + 64];
  __syncthreads();
  const float* wr = Wi + (size_t)seg*kseg*Dc + t;
  float acc = 0.f;
  for (int k = 0; k < kseg; k++) acc += Lq[k] * wr[(size_t)k*Dc];  // LDS broadcast + coalesced
  P2[((size_t)b*IKS2 + seg)*Dc + t] = acc;
}

// ---- image head norm v2: qi = b_i + sum_seg P2, then l2norm ----
__global__ __launch_bounds__(128) void k_ihead_norm2(const float* __restrict__ P2,
        const float* __restrict__ b_i, float* __restrict__ out){
  int b = blockIdx.x, d = threadIdx.x;
  float v = b_i[d];
  for (int s = 0; s < IKS2; s++) v += P2[((size_t)b*IKS2 + s)*Dc + d];
  __shared__ float red[Dc];
  red[d] = v*v; __syncthreads();
  for (int s = Dc/2; s > 0; s >>= 1){ if (d < s) red[d] += red[d+s]; __syncthreads(); }
  out[b*Dc + d] = v * rsqrtf(red[0]);
}

// ---- legacy image GEMM (fallback): split-K + LDS staging + atomics ----
constexpr int KCH = 32;
__global__ __launch_bounds__(256) void k_img_mm_legacy(const float* __restrict__ images,
        const float* __restrict__ Wimg, float* __restrict__ q, int IMG, int KSEG){
  __shared__ float Ls[KCH][NG];
  int col = blockIdx.x*256 + threadIdx.x;
  int k0  = blockIdx.y * KSEG;
  float acc[NG];
  #pragma unroll
  for (int b = 0; b < NG; b++) acc[b] = 0.f;
  for (int kk = k0; kk < k0 + KSEG; kk += KCH){
    int t = threadIdx.x;
    for (int i = t; i < KCH*NG; i += 256){
      int b = i & (NG-1), k = i >> 5;
      Ls[k][b] = images[(size_t)b*IMG + kk + k];
    }
    __syncthreads();
    for (int k = 0; k < KCH; k++){
      float w = Wimg[(size_t)(kk+k)*IMG + col];
      #pragma unroll
      for (int b = 0; b < NG; b++) acc[b] += Ls[k][b] * w;
    }
    __syncthreads();
  }
  for (int b = 0; b < NG; b++) atomicAdd(&q[(size_t)b*IMG + col], acc[b]);
}

// ---- legacy image head (fallback): 16-way split-K, uniform q loads ----
constexpr int IKS = 16;
__global__ __launch_bounds__(128) void k_ihead_mm(const float* __restrict__ q,
        const float* __restrict__ Wi, float* __restrict__ qi, int IMG){
  int b = blockIdx.x, seg = blockIdx.y, d = threadIdx.x;
  int kseg = IMG / IKS;
  const float* qr = q  + (size_t)b*IMG + (size_t)seg*kseg;
  const float* wr = Wi + (size_t)seg*kseg*Dc + d;
  float acc = 0.f;
  for (int k = 0; k < kseg; k++) acc += qr[k] * wr[(size_t)k*Dc];
  atomicAdd(&qi[b*Dc + d], acc);
}

// ---- legacy out_images = l2norm(qi) ----
__global__ __launch_bounds__(128) void k_ihead_norm(const float* __restrict__ qi,
        float* __restrict__ out){
  int b = blockIdx.x, d = threadIdx.x;
  float v = qi[b*Dc + d];
  __shared__ float red[Dc];
  red[d] = v*v; __syncthreads();
  for (int s = Dc/2; s > 0; s >>= 1){ if (d < s) red[d] += red[d+s]; __syncthreads(); }
  out[b*Dc + d] = v * rsqrtf(red[0]);
}

// ---- xw(fp16) = (relu?)x @ W  -- LDS-staged x tile (32 KB/block) ----
__global__ __launch_bounds__(256) void k_mm(const float* __restrict__ x,
        const int* __restrict__ ids, const float* __restrict__ W,
        __half* __restrict__ xwh, int N, int relu){
  __shared__ float Xs[64*Dc];          // 32 KB
  int t = threadIdx.x;
  int base = blockIdx.x*64;
  for (int i = t; i < 64*(Dc/4); i += 256){
    int lr  = i >> 5;             // local row 0..63
    int c4i = (i & 31) << 2;      // col 0,4,...,124
    int n = base + lr;
    int row = (n < N) ? (ids ? ids[n] : n) : 0;
    float4 v = *(const float4*)&x[(size_t)row*Dc + c4i];
    if (relu){
      v.x = fmaxf(v.x, 0.f); v.y = fmaxf(v.y, 0.f);
      v.z = fmaxf(v.z, 0.f); v.w = fmaxf(v.w, 0.f);
    }
    *(float4*)&Xs[lr*Dc + c4i] = v;
  }
  __syncthreads();
  int rg = t >> 5, c4 = (t & 31) << 2;
  float4 acc[8];
  #pragma unroll
  for (int r = 0; r < 8; r++) acc[r] = {0.f,0.f,0.f,0.f};
  const float* wp = W + c4;
  for (int k = 0; k < Dc; k += 4){
    float4 w0 = *(const float4*)(wp + (size_t)(k+0)*Dc);
    float4 w1 = *(const float4*)(wp + (size_t)(k+1)*Dc);
    float4 w2 = *(const float4*)(wp + (size_t)(k+2)*Dc);
    float4 w3 = *(const float4*)(wp + (size_t)(k+3)*Dc);
    #pragma unroll
    for (int r = 0; r < 8; r++){
      float4 xv = *(const float4*)&Xs[(rg + 8*r)*Dc + k];   // LDS broadcast
      acc[r].x += xv.x*w0.x + xv.y*w1.x + xv.z*w2.x + xv.w*w3.x;
      acc[r].y += xv.x*w0.y + xv.y*w1.y + xv.z*w2.y + xv.w*w3.y;
      acc[r].z += xv.x*w0.z + xv.y*w1.z + xv.z*w2.z + xv.w*w3.z;
      acc[r].w += xv.x*w0.w + xv.y*w1.w + xv.z*w2.w + xv.w*w3.w;
    }
  }
  #pragma unroll
  for (int r = 0; r < 8; r++){
    int n = base + rg + 8*r;
    if (n < N){
      union { __half2 h2[2]; uint2 u; } pk;
      pk.h2[0] = __floats2half2_rn(acc[r].x, acc[r].y);
      pk.h2[1] = __floats2half2_rn(acc[r].z, acc[r].w);
      *(uint2*)&xwh[(size_t)n*Dc + c4] = pk.u;
    }
  }
}

// ---- mean pool v2: contiguous graph ranges, register accumulation ----
constexpr int PCH = 16;
__global__ __launch_bounds__(256) void k_pool2(const float* __restrict__ x,
        const int* __restrict__ gs, float* __restrict__ pooled){
  int g = blockIdx.x, ch = blockIdx.y;
  int s = gs[g], e = gs[g+1];
  int rows = e - s;
  if (rows <= 0) return;
  int per = (rows + PCH - 1) / PCH;
  int r0 = s + ch*per;
  int r1 = min(e, r0 + per);
  if (r0 >= r1) return;
  int t = threadIdx.x;
  int lane4 = (t & 31) << 2;   // column offset (float4)
  int rg    = t >> 5;          // row subgroup 0..7
  float4 acc = {0.f,0.f,0.f,0.f};
  for (int n = r0 + rg; n < r1; n += 8){
    float4 v = *(const float4*)&x[(size_t)n*Dc + lane4];
    acc.x += v.x; acc.y += v.y; acc.z += v.z; acc.w += v.w;
  }
  __shared__ float4 red[256];
  red[t] = acc; __syncthreads();
  for (int sN = 4; sN > 0; sN >>= 1){
    if (rg < sN){
      float4 o = red[(rg+sN)*32 + (t & 31)];
      float4 m = red[t];
      m.x += o.x; m.y += o.y; m.z += o.z; m.w += o.w;
      red[t] = m;
    }
    __syncthreads();
  }
  if (rg == 0){
    float4 m = red[t];
    atomicAdd(&pooled[g*Dc + lane4 + 0], m.x);
    atomicAdd(&pooled[g*Dc + lane4 + 1], m.y);
    atomicAdd(&pooled[g*Dc + lane4 + 2], m.z);
    atomicAdd(&pooled[g*Dc + lane4 + 3], m.w);
  }
}

// ---- out_graphs = l2norm((pooled/cnt) @ W_g + b_g); cnt from gs ----
__global__ __launch_bounds__(128) void k_head(const float* __restrict__ pooled,
        const int* __restrict__ gs, const float* __restrict__ Wg,
        const float* __restrict__ bg, float* __restrict__ outg){
  int g = blockIdx.x, t = threadIdx.x;
  __shared__ float m[Dc];
  __shared__ float red[Dc];
  float c = fmaxf((float)(gs[g+1] - gs[g]), 1.f);
  m[t] = pooled[g*Dc + t] / c;
  __syncthreads();
  float acc = bg[t];
  for (int k = 0; k < Dc; k++) acc += m[k] * Wg[k*Dc + t];
  red[t] = acc*acc; __syncthreads();
  for (int s = Dc/2; s > 0; s >>= 1){ if (t < s) red[t] += red[t+s]; __syncthreads(); }
  outg[g*Dc + t] = acc * rsqrtf(red[0]);
}

extern "C" void kernel_launch(void* const* d_in, const int* in_sizes, int n_in,
                              void* d_out, int out_size, void* d_ws, size_t ws_size,
                              hipStream_t stream){
  float* out = (float*)d_out;   // reference outputs are float32

  // ---- dict-order signature verification; absmax ~= 700+code names first bad slot ----
  int fail = 0;
  auto chk = [&](bool ok, int code){ if (!fail && !ok) fail = code; };
  chk(n_in == 19, 1);
  int IMG = 0, N = 0, E = 0;
  if (!fail){
    IMG = in_sizes[0] / NG;                     // images = [NG, IMG]
    N   = in_sizes[1];                          // node_ids
    E   = in_sizes[2];                          // src
    chk(IMG >= 256 && (IMG % 256) == 0 && in_sizes[0] == NG*IMG, 2);
    chk(in_sizes[3] == E && in_sizes[4] == E, 3);        // dst, edge_attr
    chk(in_sizes[5] == N, 4);                            // batch
    chk(in_sizes[6] > 0 && (in_sizes[6] % Dc) == 0, 5);  // node_emb [VOCAB, 128]
    chk((long long)in_sizes[7] == (long long)IMG*IMG, 6);// W_img
    chk(in_sizes[8] == IMG, 7);                          // b_img
    chk((long long)in_sizes[9] == (long long)IMG*Dc, 8); // W_i
    chk(in_sizes[10] == Dc, 9);                          // b_i
    chk(in_sizes[11] == Dc*Dc && in_sizes[13] == Dc*Dc &&
        in_sizes[15] == Dc*Dc && in_sizes[17] == Dc*Dc, 10); // W1..W3, W_g
    chk(in_sizes[12] == Dc && in_sizes[14] == Dc &&
        in_sizes[16] == Dc && in_sizes[18] == Dc, 11);       // b1..b3, b_g
    chk(out_size == 2*NG*Dc, 12);
  }
  if (fail){
    k_sentinel<<<(out_size+255)/256, 256, 0, stream>>>(out, 700.f + (float)fail, out_size);
    return;
  }

  const float* images   = (const float*)d_in[0];
  const int*   node_ids = (const int*)  d_in[1];
  const int*   src      = (const int*)  d_in[2];
  const int*   dst      = (const int*)  d_in[3];
  const float* eattr    = (const float*)d_in[4];
  const int*   batch    = (const int*)  d_in[5];
  const float* emb      = (const float*)d_in[6];
  const float* W_img    = (const float*)d_in[7];
  const float* b_img    = (const float*)d_in[8];
  const float* W_i      = (const float*)d_in[9];
  const float* b_i      = (const float*)d_in[10];
  const float* W1       = (const float*)d_in[11];
  const float* b1       = (const float*)d_in[12];
  const float* W2       = (const float*)d_in[13];
  const float* b2       = (const float*)d_in[14];
  const float* W3       = (const float*)d_in[15];
  const float* b3       = (const float*)d_in[16];
  const float* W_g      = (const float*)d_in[17];
  const float* b_g      = (const float*)d_in[18];

  const int BI = NG * IMG;
  const int ND = N * Dc;
  const int ND2 = (ND + 1) / 2;       // xw fp16 region, in floats
  const int nb = (N + 255) / 256;     // scan blocks

  // ---- workspace layout ----
  // floats: xA(ND) xwh(ND2) ewn(2E) dis(N) imgreg pooled(NG*Dc)
  //   imgreg = max(NG*IKS2*Dc  [P2, fused path],  BI + NG*Dc  [q+qi, legacy])
  // ints:   packed(2N, 8B-aligned first) row_start(N+1) cntN(N) bsum(256) gs(NG+1)
  // overlays in xA region (dead until k_agg L1): rank(E ints), Ph(fp16 partials)
  size_t imgreg = (size_t)NG*IKS2*Dc;
  if ((size_t)BI + NG*Dc > imgreg) imgreg = (size_t)BI + NG*Dc;
  size_t common = (size_t)ND + ND2 + 2*(size_t)E + N + imgreg + NG*Dc;
  common += (common & 1);             // keep int region 8B aligned
  size_t csr_i  = 2*(size_t)N + (N+1) + N + 256 + (NG+1);
  size_t need   = common*sizeof(float) + csr_i*sizeof(int);
  bool overlay_ok = (size_t)ND >= (size_t)E;
  if (ws_size < need || nb > 256 || !overlay_ok){
    k_sentinel<<<(out_size+255)/256, 256, 0, stream>>>(out, 690.f, out_size);
    return;
  }

  float* ws    = (float*)d_ws;
  float* xA    = ws;  ws += (size_t)ND;
  __half* xwh  = (__half*)ws;  ws += (size_t)ND2;   // fp16 xw
  float* ewn   = ws;  ws += 2*(size_t)E;   // interleaved CSR (src, wn) pairs
  float* dis   = ws;  ws += N;
  float* ireg  = ws;  ws += imgreg;        // P2 (fused) or q+qi (legacy)
  float* pooled= ws;  ws += NG*Dc;
  ws = (float*)d_ws + common;
  unsigned long long* packed = (unsigned long long*)ws;   // 2N ints, dedicated
  int* iw        = (int*)ws + 2*(size_t)N;
  int* row_start = iw;  iw += N+1;
  int* cntN      = iw;  iw += N;
  int* bsum      = iw;  iw += 256;
  int* gs        = iw;  iw += NG+1;

  // overlays in xA (image partials reuse this region BEFORE the graph path)
  int* rank = (int*)xA;                 // E ints
  __half* Ph = (__half*)xA;             // fp16 image-GEMM partials

  int nbz = (nb > (NG*Dc+255)/256) ? nb : (NG*Dc+255)/256;
  k_init2<<<nbz+1, 256, 0, stream>>>(pooled, packed, batch, gs, N, nbz);

  // ---- image path (partials overlay the xA/xwh/ewn region) ----
  int nseg = IMG / KS3;
  bool v3ok = ((IMG % 512) == 0) &&
              ((size_t)nseg*BI <= 2*((size_t)ND + ND2 + 2*(size_t)E));
  bool fused = v3ok && (IMG == IKS2*64);   // IMG == 4096
  if (fused){
    k_img_mm3    <<<dim3(IMG/512, nseg), 256, 0, stream>>>(images, W_img, Ph, IMG);
    k_ihead_mm3  <<<dim3(NG, IKS2), 128, 0, stream>>>(Ph, b_img, W_i, ireg, IMG, nseg);
    k_ihead_norm2<<<NG, Dc, 0, stream>>>(ireg, b_i, out);
  } else {
    float* q  = ireg;
    float* qi = ireg + BI;
    k_init_iq<<<(BI+255)/256, 256, 0, stream>>>(b_img, q, b_i, qi, BI, IMG);
    const int KSPLIT = ((IMG % (16*KCH)) == 0) ? 16 : 8;
    k_img_mm_legacy<<<dim3(IMG/256, KSPLIT), 256, 0, stream>>>(images, W_img, q, IMG, IMG/KSPLIT);
    k_ihead_mm <<<dim3(NG, IKS), Dc, 0, stream>>>(q, W_i, qi, IMG);
    k_ihead_norm<<<NG, Dc, 0, stream>>>(qi, out);
  }

  // ---- graph preprocessing: 1 packed atomic/edge, then atomic-free CSR ----
  k_pack_count<<<(E+255)/256, 256, 0, stream>>>(dst, eattr, packed, rank, E);
  k_dis2s     <<<nb, 256, 0, stream>>>(packed, dis, cntN, bsum, N);
  k_scan_bsum <<<1,  256, 0, stream>>>(bsum, nb, row_start, N, E);
  k_scan_final<<<nb, 256, 0, stream>>>(cntN, bsum, row_start, N);
  k_fill2     <<<(E+255)/256, 256, 0, stream>>>(src, dst, eattr, dis, rank,
                                                row_start, (float2*)ewn, E);

  // ---- GCN layers: layer 1 reads emb through node_ids (fused gather) ----
  const float* Wl[3] = {W1, W2, W3};
  const float* bl[3] = {b1, b2, b3};
  for (int l = 0; l < 3; l++){
    const float* xin = (l == 0) ? emb : xA;
    const int*   ids = (l == 0) ? node_ids : nullptr;
    k_mm <<<(N+63)/64, 256, 0, stream>>>(xin, ids, Wl[l], xwh, N, l > 0);
    k_agg<<<(N+1)/2, 128, 0, stream>>>(xwh, row_start, (const float2*)ewn, dis, bl[l], xA, N);
  }

  k_pool2<<<dim3(NG, PCH), 256, 0, stream>>>(xA, gs, pooled);
  k_head <<<NG, Dc, 0, stream>>>(pooled, gs, W_g, b_g, out + NG*Dc);
}

// Round 14
// 421.775 us; speedup vs baseline: 1.0198x; 1.0198x over previous
//
#include <hip/hip_runtime.h>
#include <hip/hip_bf16.h>
#include <hip/hip_fp16.h>

constexpr int Dc = 128;   // feature dim
constexpr int NG = 32;    // num graphs / batch size

// ---- sentinel: encode a diagnostic code in the output magnitude ----
__global__ void k_sentinel(float* __restrict__ out, float val, int n){
  int i = blockIdx.x*256 + threadIdx.x;
  if (i < n) out[i] = val;
}

// ---- init2: pooled = 0, packed = 0, last block does graph bounds ----
__global__ void k_init2(float* __restrict__ pooled,
                        unsigned long long* __restrict__ packed,
                        const int* __restrict__ batch, int* __restrict__ gs,
                        int N, int nbz){
  if ((int)blockIdx.x == nbz){
    int g = threadIdx.x;
    if (g > NG) return;
    int lo = 0, hi = N;
    while (lo < hi){ int mid = (lo+hi)>>1; if (batch[mid] < g) lo = mid+1; else hi = mid; }
    gs[g] = lo;
    return;
  }
  int i = blockIdx.x*256 + threadIdx.x;
  if (i < NG*Dc) pooled[i] = 0.f;
  if (i < N) packed[i] = 0ULL;
}

// ---- fallback init: q = b_img, qi = b_i (legacy image path only) ----
__global__ void k_init_iq(const float* __restrict__ b_img, float* __restrict__ q,
                          const float* __restrict__ b_i, float* __restrict__ qi,
                          int BI, int IMG){
  int i = blockIdx.x*256 + threadIdx.x;
  if (i < BI) q[i] = b_img[i % IMG];
  if (i < NG*Dc) qi[i] = b_i[i & (Dc-1)];
}

// ---- ONE packed atomic per edge: hi 24 bits = in-degree count,
//      lo 40 bits = 20.20 fixed-point sum of edge weights.
//      Returned old value's count field = this edge's rank within its row. ----
__global__ void k_pack_count(const int* __restrict__ dst, const float* __restrict__ ew,
        unsigned long long* __restrict__ packed, int* __restrict__ rank, int E){
  int e = blockIdx.x*256 + threadIdx.x;
  if (e >= E) return;
  unsigned long long fx = (unsigned long long)(ew[e]*1048576.f + 0.5f);  // 20.20 fixed
  unsigned long long old = atomicAdd(&packed[dst[e]], (1ULL<<40) | fx);
  rank[e] = (int)(old >> 40);
}

// ---- fused unpack + scan_partial: cntN, dis, and per-block count sums ----
__global__ __launch_bounds__(256) void k_dis2s(const unsigned long long* __restrict__ packed,
        float* __restrict__ dis, int* __restrict__ cntN, int* __restrict__ bsum, int N){
  __shared__ int red[256];
  int t = threadIdx.x, i = blockIdx.x*256 + t;
  int c = 0;
  if (i < N){
    unsigned long long p = packed[i];
    c = (int)(p >> 40);
    cntN[i] = c;
    float deg = 1.0f + (float)(p & ((1ULL<<40)-1)) * (1.0f/1048576.0f);
    dis[i] = rsqrtf(deg);
  }
  red[t] = c;
  __syncthreads();
  for (int s = 128; s > 0; s >>= 1){ if (t < s) red[t] += red[t+s]; __syncthreads(); }
  if (t == 0) bsum[blockIdx.x] = red[0];
}

__global__ __launch_bounds__(256) void k_scan_bsum(int* __restrict__ bsum, int nb,
        int* __restrict__ row_start, int N, int E){
  __shared__ int sc[256];
  int t = threadIdx.x;
  int orig = (t < nb) ? bsum[t] : 0;
  sc[t] = orig;
  __syncthreads();
  for (int off = 1; off < 256; off <<= 1){
    int v = (t >= off) ? sc[t-off] : 0;
    __syncthreads();
    sc[t] += v;
    __syncthreads();
  }
  if (t < nb) bsum[t] = sc[t] - orig;   // exclusive
  if (t == 0) row_start[N] = E;
}

__global__ __launch_bounds__(256) void k_scan_final(const int* __restrict__ cnt,
        const int* __restrict__ bsum, int* __restrict__ row_start, int N){
  __shared__ int sc[256];
  int t = threadIdx.x, i = blockIdx.x*256 + t;
  int orig = (i < N) ? cnt[i] : 0;
  sc[t] = orig;
  __syncthreads();
  for (int off = 1; off < 256; off <<= 1){
    int v = (t >= off) ? sc[t-off] : 0;
    __syncthreads();
    sc[t] += v;
    __syncthreads();
  }
  if (i < N) row_start[i] = bsum[blockIdx.x] + sc[t] - orig;
}

// ---- fill CSR, NO atomics: pos = row_start[dst] + rank; one interleaved
//      8B store per edge: (src, dis[s]*ew*dis[d]) ----
__global__ void k_fill2(const int* __restrict__ src, const int* __restrict__ dst,
        const float* __restrict__ ew, const float* __restrict__ dis,
        const int* __restrict__ rank, const int* __restrict__ row_start,
        float2* __restrict__ ewn, int E){
  int e = blockIdx.x*256 + threadIdx.x;
  if (e >= E) return;
  int s = src[e], d = dst[e];
  int pos = row_start[d] + rank[e];
  float2 v;
  v.x = __int_as_float(s);
  v.y = dis[s] * ew[e] * dis[d];
  ewn[pos] = v;
}

// ---- pull aggregation over fp16 xw: 2 nodes/block (1 per wave),
//      lane owns 2 cols (half2 gather = 4B/lane, full 256B row per wave). ----
__global__ __launch_bounds__(128) void k_agg(const __half* __restrict__ xwh,
        const int* __restrict__ row_start, const float2* __restrict__ ewn,
        const float* __restrict__ dis, const float* __restrict__ bias,
        float* __restrict__ xo, int N){
  int n = blockIdx.x*2 + (threadIdx.x >> 6);
  if (n >= N) return;
  int l = threadIdx.x & 63;          // lane: cols 2l, 2l+1
  int c = l << 1;
  float dv = dis[n];
  float2 self = __half22float2(*(const __half2*)&xwh[(size_t)n*Dc + c]);
  float2 acc;
  acc.x = bias[c]   + self.x*dv*dv;
  acc.y = bias[c+1] + self.y*dv*dv;
  int j = row_start[n], j1 = row_start[n+1];
  for (; j + 3 < j1; j += 4){
    float2 e0 = ewn[j],   e1 = ewn[j+1], e2 = ewn[j+2], e3 = ewn[j+3];
    int   s0 = __float_as_int(e0.x), s1 = __float_as_int(e1.x);
    int   s2 = __float_as_int(e2.x), s3 = __float_as_int(e3.x);
    float2 v0 = __half22float2(*(const __half2*)&xwh[(size_t)s0*Dc + c]);
    float2 v1 = __half22float2(*(const __half2*)&xwh[(size_t)s1*Dc + c]);
    float2 v2 = __half22float2(*(const __half2*)&xwh[(size_t)s2*Dc + c]);
    float2 v3 = __half22float2(*(const __half2*)&xwh[(size_t)s3*Dc + c]);
    acc.x += v0.x*e0.y + v1.x*e1.y + v2.x*e2.y + v3.x*e3.y;
    acc.y += v0.y*e0.y + v1.y*e1.y + v2.y*e2.y + v3.y*e3.y;
  }
  for (; j < j1; j++){
    float2 ee = ewn[j];
    float2 v = __half22float2(*(const __half2*)&xwh[(size_t)__float_as_int(ee.x)*Dc + c]);
    acc.x += v.x*ee.y;
    acc.y += v.y*ee.y;
  }
  *(float2*)&xo[(size_t)n*Dc + c] = acc;
}

// ==== image GEMM v5 (best measured, R12): KS3=32, fp16 partials, 2-row W
//      prefetch, __launch_bounds__(256,1) so the 64-float acc stays in VGPRs
//      (R10's VGPR_Count=44 proved the default heuristic spilled it). ====
constexpr int KS3 = 32;
__global__ __launch_bounds__(256, 1) void k_img_mm3(const float* __restrict__ images,
        const float* __restrict__ Wimg, __half* __restrict__ P, int IMG){
  __shared__ float Ls[NG][KS3];
  int t = threadIdx.x;
  int col = blockIdx.x*512 + (t << 1);
  int k0  = blockIdx.y * KS3;
  for (int i = t; i < NG*KS3; i += 256){
    int b = i >> 5, k = i & (KS3-1);
    Ls[b][k] = images[(size_t)b*IMG + k0 + k];
  }
  __syncthreads();
  float2 acc[NG];
  #pragma unroll
  for (int b = 0; b < NG; b++){ acc[b].x = 0.f; acc[b].y = 0.f; }
  const float* wp = Wimg + (size_t)k0*IMG + col;
  float2 w0 = *(const float2*)wp;
  float2 w1 = *(const float2*)(wp + IMG);
  for (int k = 0; k < KS3; k += 2){
    float2 nw0 = w0, nw1 = w1;
    if (k + 2 < KS3){
      nw0 = *(const float2*)(wp + 2*(size_t)IMG);
      nw1 = *(const float2*)(wp + 3*(size_t)IMG);
    }
    #pragma unroll
    for (int b = 0; b < NG; b++){
      float2 iv = *(const float2*)&Ls[b][k];   // broadcast ds_read_b64
      acc[b].x += iv.x*w0.x + iv.y*w1.x;
      acc[b].y += iv.x*w0.y + iv.y*w1.y;
    }
    w0 = nw0; w1 = nw1;
    wp += 2*(size_t)IMG;
  }
  size_t BIs = (size_t)NG*IMG;
  size_t base = (size_t)blockIdx.y*BIs + col;
  #pragma unroll
  for (int b = 0; b < NG; b++)
    *(__half2*)&P[base + (size_t)b*IMG] = __floats2half2_rn(acc[b].x, acc[b].y);
}

// ---- image head v3 (fused): stage Lq[64] = b_img-slice + sum_g Ph, then
//      GEMM slice vs W_i; write per-(b,seg) partials (no atomics). IMG==4096. ----
constexpr int IKS2 = 64;
__global__ __launch_bounds__(128) void k_ihead_mm3(const __half* __restrict__ Ph,
        const float* __restrict__ b_img, const float* __restrict__ Wi,
        float* __restrict__ P2, int IMG, int nseg){
  int b = blockIdx.x, seg = blockIdx.y, t = threadIdx.x;
  const int kseg = 64;                    // IMG / IKS2 with IMG == 4096
  int BI = NG * IMG;
  __shared__ float Ls2[128];
  __shared__ float Lq[64];
  int c = t & 63, gh = t >> 6;
  size_t base = (size_t)b*IMG + seg*kseg + c;
  float part = 0.f;
  for (int g = gh; g < nseg; g += 2)
    part += __half2float(Ph[(size_t)g*BI + base]);
  Ls2[t] = part;
  __syncthreads();
  if (t < 64) Lq[t] = b_img[seg*kseg + t] + Ls2[t] + Ls2[t + 64];
  __syncthreads();
  const float* wr = Wi + (size_t)seg*kseg*Dc + t;
  float acc = 0.f;
  for (int k = 0; k < kseg; k++) acc += Lq[k] * wr[(size_t)k*Dc];  // LDS broadcast + coalesced
  P2[((size_t)b*IKS2 + seg)*Dc + t] = acc;
}

// ---- image head norm v2: qi = b_i + sum_seg P2, then l2norm ----
__global__ __launch_bounds__(128) void k_ihead_norm2(const float* __restrict__ P2,
        const float* __restrict__ b_i, float* __restrict__ out){
  int b = blockIdx.x, d = threadIdx.x;
  float v = b_i[d];
  for (int s = 0; s < IKS2; s++) v += P2[((size_t)b*IKS2 + s)*Dc + d];
  __shared__ float red[Dc];
  red[d] = v*v; __syncthreads();
  for (int s = Dc/2; s > 0; s >>= 1){ if (d < s) red[d] += red[d+s]; __syncthreads(); }
  out[b*Dc + d] = v * rsqrtf(red[0]);
}

// ---- legacy image GEMM (fallback): split-K + LDS staging + atomics ----
constexpr int KCH = 32;
__global__ __launch_bounds__(256) void k_img_mm_legacy(const float* __restrict__ images,
        const float* __restrict__ Wimg, float* __restrict__ q, int IMG, int KSEG){
  __shared__ float Ls[KCH][NG];
  int col = blockIdx.x*256 + threadIdx.x;
  int k0  = blockIdx.y * KSEG;
  float acc[NG];
  #pragma unroll
  for (int b = 0; b < NG; b++) acc[b] = 0.f;
  for (int kk = k0; kk < k0 + KSEG; kk += KCH){
    int t = threadIdx.x;
    for (int i = t; i < KCH*NG; i += 256){
      int b = i & (NG-1), k = i >> 5;
      Ls[k][b] = images[(size_t)b*IMG + kk + k];
    }
    __syncthreads();
    for (int k = 0; k < KCH; k++){
      float w = Wimg[(size_t)(kk+k)*IMG + col];
      #pragma unroll
      for (int b = 0; b < NG; b++) acc[b] += Ls[k][b] * w;
    }
    __syncthreads();
  }
  for (int b = 0; b < NG; b++) atomicAdd(&q[(size_t)b*IMG + col], acc[b]);
}

// ---- legacy image head (fallback): 16-way split-K, uniform q loads ----
constexpr int IKS = 16;
__global__ __launch_bounds__(128) void k_ihead_mm(const float* __restrict__ q,
        const float* __restrict__ Wi, float* __restrict__ qi, int IMG){
  int b = blockIdx.x, seg = blockIdx.y, d = threadIdx.x;
  int kseg = IMG / IKS;
  const float* qr = q  + (size_t)b*IMG + (size_t)seg*kseg;
  const float* wr = Wi + (size_t)seg*kseg*Dc + d;
  float acc = 0.f;
  for (int k = 0; k < kseg; k++) acc += qr[k] * wr[(size_t)k*Dc];
  atomicAdd(&qi[b*Dc + d], acc);
}

// ---- legacy out_images = l2norm(qi) ----
__global__ __launch_bounds__(128) void k_ihead_norm(const float* __restrict__ qi,
        float* __restrict__ out){
  int b = blockIdx.x, d = threadIdx.x;
  float v = qi[b*Dc + d];
  __shared__ float red[Dc];
  red[d] = v*v; __syncthreads();
  for (int s = Dc/2; s > 0; s >>= 1){ if (d < s) red[d] += red[d+s]; __syncthreads(); }
  out[b*Dc + d] = v * rsqrtf(red[0]);
}

// ---- xw(fp16) = (relu?)x @ W  -- LDS-staged x tile (32 KB/block) ----
__global__ __launch_bounds__(256) void k_mm(const float* __restrict__ x,
        const int* __restrict__ ids, const float* __restrict__ W,
        __half* __restrict__ xwh, int N, int relu){
  __shared__ float Xs[64*Dc];          // 32 KB
  int t = threadIdx.x;
  int base = blockIdx.x*64;
  for (int i = t; i < 64*(Dc/4); i += 256){
    int lr  = i >> 5;             // local row 0..63
    int c4i = (i & 31) << 2;      // col 0,4,...,124
    int n = base + lr;
    int row = (n < N) ? (ids ? ids[n] : n) : 0;
    float4 v = *(const float4*)&x[(size_t)row*Dc + c4i];
    if (relu){
      v.x = fmaxf(v.x, 0.f); v.y = fmaxf(v.y, 0.f);
      v.z = fmaxf(v.z, 0.f); v.w = fmaxf(v.w, 0.f);
    }
    *(float4*)&Xs[lr*Dc + c4i] = v;
  }
  __syncthreads();
  int rg = t >> 5, c4 = (t & 31) << 2;
  float4 acc[8];
  #pragma unroll
  for (int r = 0; r < 8; r++) acc[r] = {0.f,0.f,0.f,0.f};
  const float* wp = W + c4;
  for (int k = 0; k < Dc; k += 4){
    float4 w0 = *(const float4*)(wp + (size_t)(k+0)*Dc);
    float4 w1 = *(const float4*)(wp + (size_t)(k+1)*Dc);
    float4 w2 = *(const float4*)(wp + (size_t)(k+2)*Dc);
    float4 w3 = *(const float4*)(wp + (size_t)(k+3)*Dc);
    #pragma unroll
    for (int r = 0; r < 8; r++){
      float4 xv = *(const float4*)&Xs[(rg + 8*r)*Dc + k];   // LDS broadcast
      acc[r].x += xv.x*w0.x + xv.y*w1.x + xv.z*w2.x + xv.w*w3.x;
      acc[r].y += xv.x*w0.y + xv.y*w1.y + xv.z*w2.y + xv.w*w3.y;
      acc[r].z += xv.x*w0.z + xv.y*w1.z + xv.z*w2.z + xv.w*w3.z;
      acc[r].w += xv.x*w0.w + xv.y*w1.w + xv.z*w2.w + xv.w*w3.w;
    }
  }
  #pragma unroll
  for (int r = 0; r < 8; r++){
    int n = base + rg + 8*r;
    if (n < N){
      union { __half2 h2[2]; uint2 u; } pk;
      pk.h2[0] = __floats2half2_rn(acc[r].x, acc[r].y);
      pk.h2[1] = __floats2half2_rn(acc[r].z, acc[r].w);
      *(uint2*)&xwh[(size_t)n*Dc + c4] = pk.u;
    }
  }
}

// ---- mean pool v2: contiguous graph ranges, register accumulation ----
constexpr int PCH = 16;
__global__ __launch_bounds__(256) void k_pool2(const float* __restrict__ x,
        const int* __restrict__ gs, float* __restrict__ pooled){
  int g = blockIdx.x, ch = blockIdx.y;
  int s = gs[g], e = gs[g+1];
  int rows = e - s;
  if (rows <= 0) return;
  int per = (rows + PCH - 1) / PCH;
  int r0 = s + ch*per;
  int r1 = min(e, r0 + per);
  if (r0 >= r1) return;
  int t = threadIdx.x;
  int lane4 = (t & 31) << 2;   // column offset (float4)
  int rg    = t >> 5;          // row subgroup 0..7
  float4 acc = {0.f,0.f,0.f,0.f};
  for (int n = r0 + rg; n < r1; n += 8){
    float4 v = *(const float4*)&x[(size_t)n*Dc + lane4];
    acc.x += v.x; acc.y += v.y; acc.z += v.z; acc.w += v.w;
  }
  __shared__ float4 red[256];
  red[t] = acc; __syncthreads();
  for (int sN = 4; sN > 0; sN >>= 1){
    if (rg < sN){
      float4 o = red[(rg+sN)*32 + (t & 31)];
      float4 m = red[t];
      m.x += o.x; m.y += o.y; m.z += o.z; m.w += o.w;
      red[t] = m;
    }
    __syncthreads();
  }
  if (rg == 0){
    float4 m = red[t];
    atomicAdd(&pooled[g*Dc + lane4 + 0], m.x);
    atomicAdd(&pooled[g*Dc + lane4 + 1], m.y);
    atomicAdd(&pooled[g*Dc + lane4 + 2], m.z);
    atomicAdd(&pooled[g*Dc + lane4 + 3], m.w);
  }
}

// ---- out_graphs = l2norm((pooled/cnt) @ W_g + b_g); cnt from gs ----
__global__ __launch_bounds__(128) void k_head(const float* __restrict__ pooled,
        const int* __restrict__ gs, const float* __restrict__ Wg,
        const float* __restrict__ bg, float* __restrict__ outg){
  int g = blockIdx.x, t = threadIdx.x;
  __shared__ float m[Dc];
  __shared__ float red[Dc];
  float c = fmaxf((float)(gs[g+1] - gs[g]), 1.f);
  m[t] = pooled[g*Dc + t] / c;
  __syncthreads();
  float acc = bg[t];
  for (int k = 0; k < Dc; k++) acc += m[k] * Wg[k*Dc + t];
  red[t] = acc*acc; __syncthreads();
  for (int s = Dc/2; s > 0; s >>= 1){ if (t < s) red[t] += red[t+s]; __syncthreads(); }
  outg[g*Dc + t] = acc * rsqrtf(red[0]);
}

extern "C" void kernel_launch(void* const* d_in, const int* in_sizes, int n_in,
                              void* d_out, int out_size, void* d_ws, size_t ws_size,
                              hipStream_t stream){
  float* out = (float*)d_out;   // reference outputs are float32

  // ---- dict-order signature verification; absmax ~= 700+code names first bad slot ----
  int fail = 0;
  auto chk = [&](bool ok, int code){ if (!fail && !ok) fail = code; };
  chk(n_in == 19, 1);
  int IMG = 0, N = 0, E = 0;
  if (!fail){
    IMG = in_sizes[0] / NG;                     // images = [NG, IMG]
    N   = in_sizes[1];                          // node_ids
    E   = in_sizes[2];                          // src
    chk(IMG >= 256 && (IMG % 256) == 0 && in_sizes[0] == NG*IMG, 2);
    chk(in_sizes[3] == E && in_sizes[4] == E, 3);        // dst, edge_attr
    chk(in_sizes[5] == N, 4);                            // batch
    chk(in_sizes[6] > 0 && (in_sizes[6] % Dc) == 0, 5);  // node_emb [VOCAB, 128]
    chk((long long)in_sizes[7] == (long long)IMG*IMG, 6);// W_img
    chk(in_sizes[8] == IMG, 7);                          // b_img
    chk((long long)in_sizes[9] == (long long)IMG*Dc, 8); // W_i
    chk(in_sizes[10] == Dc, 9);                          // b_i
    chk(in_sizes[11] == Dc*Dc && in_sizes[13] == Dc*Dc &&
        in_sizes[15] == Dc*Dc && in_sizes[17] == Dc*Dc, 10); // W1..W3, W_g
    chk(in_sizes[12] == Dc && in_sizes[14] == Dc &&
        in_sizes[16] == Dc && in_sizes[18] == Dc, 11);       // b1..b3, b_g
    chk(out_size == 2*NG*Dc, 12);
  }
  if (fail){
    k_sentinel<<<(out_size+255)/256, 256, 0, stream>>>(out, 700.f + (float)fail, out_size);
    return;
  }

  const float* images   = (const float*)d_in[0];
  const int*   node_ids = (const int*)  d_in[1];
  const int*   src      = (const int*)  d_in[2];
  const int*   dst      = (const int*)  d_in[3];
  const float* eattr    = (const float*)d_in[4];
  const int*   batch    = (const int*)  d_in[5];
  const float* emb      = (const float*)d_in[6];
  const float* W_img    = (const float*)d_in[7];
  const float* b_img    = (const float*)d_in[8];
  const float* W_i      = (const float*)d_in[9];
  const float* b_i      = (const float*)d_in[10];
  const float* W1       = (const float*)d_in[11];
  const float* b1       = (const float*)d_in[12];
  const float* W2       = (const float*)d_in[13];
  const float* b2       = (const float*)d_in[14];
  const float* W3       = (const float*)d_in[15];
  const float* b3       = (const float*)d_in[16];
  const float* W_g      = (const float*)d_in[17];
  const float* b_g      = (const float*)d_in[18];

  const int BI = NG * IMG;
  const int ND = N * Dc;
  const int ND2 = (ND + 1) / 2;       // xw fp16 region, in floats
  const int nb = (N + 255) / 256;     // scan blocks

  // ---- workspace layout ----
  // floats: xA(ND) xwh(ND2) ewn(2E) dis(N) imgreg pooled(NG*Dc)
  //   imgreg = max(NG*IKS2*Dc  [P2, fused path],  BI + NG*Dc  [q+qi, legacy])
  // ints:   packed(2N, 8B-aligned first) row_start(N+1) cntN(N) bsum(256) gs(NG+1)
  // overlays in xA region (dead until k_agg L1): rank(E ints), Ph(fp16 partials)
  size_t imgreg = (size_t)NG*IKS2*Dc;
  if ((size_t)BI + NG*Dc > imgreg) imgreg = (size_t)BI + NG*Dc;
  size_t common = (size_t)ND + ND2 + 2*(size_t)E + N + imgreg + NG*Dc;
  common += (common & 1);             // keep int region 8B aligned
  size_t csr_i  = 2*(size_t)N + (N+1) + N + 256 + (NG+1);
  size_t need   = common*sizeof(float) + csr_i*sizeof(int);
  bool overlay_ok = (size_t)ND >= (size_t)E;
  if (ws_size < need || nb > 256 || !overlay_ok){
    k_sentinel<<<(out_size+255)/256, 256, 0, stream>>>(out, 690.f, out_size);
    return;
  }

  float* ws    = (float*)d_ws;
  float* xA    = ws;  ws += (size_t)ND;
  __half* xwh  = (__half*)ws;  ws += (size_t)ND2;   // fp16 xw
  float* ewn   = ws;  ws += 2*(size_t)E;   // interleaved CSR (src, wn) pairs
  float* dis   = ws;  ws += N;
  float* ireg  = ws;  ws += imgreg;        // P2 (fused) or q+qi (legacy)
  float* pooled= ws;  ws += NG*Dc;
  ws = (float*)d_ws + common;
  unsigned long long* packed = (unsigned long long*)ws;   // 2N ints, dedicated
  int* iw        = (int*)ws + 2*(size_t)N;
  int* row_start = iw;  iw += N+1;
  int* cntN      = iw;  iw += N;
  int* bsum      = iw;  iw += 256;
  int* gs        = iw;  iw += NG+1;

  // overlays in xA (image partials reuse this region BEFORE the graph path)
  int* rank = (int*)xA;                 // E ints
  __half* Ph = (__half*)xA;             // fp16 image-GEMM partials

  int nbz = (nb > (NG*Dc+255)/256) ? nb : (NG*Dc+255)/256;
  k_init2<<<nbz+1, 256, 0, stream>>>(pooled, packed, batch, gs, N, nbz);

  // ---- image path (partials overlay the xA/xwh/ewn region) ----
  int nseg = IMG / KS3;
  bool v3ok = ((IMG % 512) == 0) &&
              ((size_t)nseg*BI <= 2*((size_t)ND + ND2 + 2*(size_t)E));
  bool fused = v3ok && (IMG == IKS2*64);   // IMG == 4096
  if (fused){
    k_img_mm3    <<<dim3(IMG/512, nseg), 256, 0, stream>>>(images, W_img, Ph, IMG);
    k_ihead_mm3  <<<dim3(NG, IKS2), 128, 0, stream>>>(Ph, b_img, W_i, ireg, IMG, nseg);
    k_ihead_norm2<<<NG, Dc, 0, stream>>>(ireg, b_i, out);
  } else {
    float* q  = ireg;
    float* qi = ireg + BI;
    k_init_iq<<<(BI+255)/256, 256, 0, stream>>>(b_img, q, b_i, qi, BI, IMG);
    const int KSPLIT = ((IMG % (16*KCH)) == 0) ? 16 : 8;
    k_img_mm_legacy<<<dim3(IMG/256, KSPLIT), 256, 0, stream>>>(images, W_img, q, IMG, IMG/KSPLIT);
    k_ihead_mm <<<dim3(NG, IKS), Dc, 0, stream>>>(q, W_i, qi, IMG);
    k_ihead_norm<<<NG, Dc, 0, stream>>>(qi, out);
  }

  // ---- graph preprocessing: 1 packed atomic/edge, then atomic-free CSR ----
  k_pack_count<<<(E+255)/256, 256, 0, stream>>>(dst, eattr, packed, rank, E);
  k_dis2s     <<<nb, 256, 0, stream>>>(packed, dis, cntN, bsum, N);
  k_scan_bsum <<<1,  256, 0, stream>>>(bsum, nb, row_start, N, E);
  k_scan_final<<<nb, 256, 0, stream>>>(cntN, bsum, row_start, N);
  k_fill2     <<<(E+255)/256, 256, 0, stream>>>(src, dst, eattr, dis, rank,
                                                row_start, (float2*)ewn, E);

  // ---- GCN layers: layer 1 reads emb through node_ids (fused gather) ----
  const float* Wl[3] = {W1, W2, W3};
  const float* bl[3] = {b1, b2, b3};
  for (int l = 0; l < 3; l++){
    const float* xin = (l == 0) ? emb : xA;
    const int*   ids = (l == 0) ? node_ids : nullptr;
    k_mm <<<(N+63)/64, 256, 0, stream>>>(xin, ids, Wl[l], xwh, N, l > 0);
    k_agg<<<(N+1)/2, 128, 0, stream>>>(xwh, row_start, (const float2*)ewn, dis, bl[l], xA, N);
  }

  k_pool2<<<dim3(NG, PCH), 256, 0, stream>>>(xA, gs, pooled);
  k_head <<<NG, Dc, 0, stream>>>(pooled, gs, W_g, b_g, out + NG*Dc);
}